// Round 1
// baseline (259.815 us; speedup 1.0000x reference)
//
#include <hip/hip_runtime.h>

// Instant-NGP hash encode (16 levels, F=2) + 32->64->64->8 MLP via MFMA,
// outer trilinear over 8 corners of a 512^3 grid.
//
// R3-R6: MFMA MLP, lane-local layer transitions, spill-free.
// R8/R9: weights in LDS, BLOCK 256. R10: hashed levels bf16 in d_ws.
// R11: compacted fine levels (8MB random region), FETCH -> 313MB.
// R12 (this round): LDS-pipe + VALU restructure.
//   - Weights live in 56 VGPRs (loaded once per block): removes the per-group
//     14x ds_read_b128 (112 cyc vs 67 MFMA cyc -- weight re-reads cost more
//     than the matmul), removes staging + the block barrier entirely
//     (x-exchange is within-wave: ev = wv*64+g*16+col).
//   - LDS = 16KB x-region only, XOR quad swizzle kills the stride-64B bank
//     conflicts (1.1e7 -> ~0).
//   - v_cvt_pk_bf16_f32 replaces manual bf16_rn pair-packing (RNE == RNE).
//   - Persistent ITER=4 tiles amortize weight loads; prep fused to 1 launch.

typedef __attribute__((ext_vector_type(8))) short short8_t;
typedef __attribute__((ext_vector_type(4))) float f32x4;

static constexpr unsigned kT    = 1u << 19;
static constexpr unsigned kMask = kT - 1u;
static constexpr unsigned cP1   = 2654435761u;
static constexpr unsigned cP2   = 805459861u;
static constexpr int      BLOCK = 256;
static constexpr int      ITER  = 4;       // tiles per block (persistent)
static constexpr int      TOFF  = 4096;    // d_ws dword offset of tables
static constexpr size_t   WS_NEED = ((size_t)TOFF + (1u << 21)) * 4;  // 16KB+8MB

static __device__ __forceinline__ unsigned bf16_rn(float x) {
    unsigned u = __float_as_uint(x);
    return (u + 0x7fffu + ((u >> 16) & 1u)) >> 16;   // round-to-nearest-even
}

static __device__ __forceinline__ float2 bf2dec(unsigned u) {
    return make_float2(__uint_as_float(u << 16),
                       __uint_as_float(u & 0xffff0000u));
}

// packed f32x2 -> bf16x2, RNE (bit-identical to bf16_rn pair). lo in low 16.
static __device__ __forceinline__ unsigned cvtpk(float lo, float hi) {
    unsigned r;
    asm("v_cvt_pk_bf16_f32 %0, %1, %2" : "=v"(r) : "v"(lo), "v"(hi));
    return r;
}

static __device__ __forceinline__ f32x4 mfma16(short8_t a, short8_t b, f32x4 c) {
    return __builtin_amdgcn_mfma_f32_16x16x32_bf16(a, b, c, 0, 0, 0);
}

// ---- fused prep: [0,ncc) coarse bf16 convert; [ncc,ncc+ncf) fine
// convert+compact; tail 4 blocks = weight pre-swizzle (14 tiles x 64 lanes).
__global__ __launch_bounds__(256)
void prep_all(const float* __restrict__ W0, const float* __restrict__ W1,
              const float* __restrict__ W2, const float2* __restrict__ tbl,
              unsigned* __restrict__ ws, int ncc, int ncf)
{
    const int bx = blockIdx.x, tid = threadIdx.x;
    if (bx < ncc) {
        // coarse levels 3,4: fp32x2 -> packed bf16x2 (pairs of entries)
        const int i = bx * 256 + tid;                // < 2^19
        const float4 v = ((const float4*)(tbl + (size_t)3 * kT))[i];
        ((uint2*)(ws + TOFF))[i] =
            make_uint2(bf16_rn(v.x) | (bf16_rn(v.y) << 16),
                       bf16_rn(v.z) | (bf16_rn(v.w) << 16));
    } else if (bx < ncc + ncf) {
        // fine level 5+s entry (j<<s) -> compact slot j at fineOff(s)
        const int i = (bx - ncc) * 256 + tid;        // < 2^20 - 2^9
        const unsigned vv = (1u << 20) - 1u - (unsigned)i;
        const int s = __clz((int)vv) - 12;           // 0..10
        const unsigned fo = (1u << 20) - ((1u << 20) >> s);
        const unsigned j = (unsigned)i - fo;
        const float2 e = tbl[((size_t)(5 + s) << 19) + ((size_t)j << s)];
        (ws + TOFF + (1u << 20))[i] = bf16_rn(e.x) | (bf16_rn(e.y) << 16);
    } else {
        // weights: A-frag order, bf16 RNE. tiles 0..3 = W0; 4..11 = W1
        // (mt=(t-4)>>1, kt=(t-4)&1, K pi-permuted); 12..13 = W2 (cols>=8 zero)
        const int t = (bx - ncc - ncf) * 4 + (tid >> 6);
        if (t >= 14) return;
        const int lane = tid & 63;
        const int n = lane & 15, q = lane >> 4;
        unsigned hi[4];
        #pragma unroll
        for (int d = 0; d < 4; ++d) {
            unsigned h2[2];
            #pragma unroll
            for (int s = 0; s < 2; ++s) {
                const int j = d * 2 + s;
                float v;
                if (t < 4) {
                    v = W0[(q * 8 + j) * 64 + t * 16 + n];
                } else {
                    const int kp = (j < 4) ? (q * 4 + j) : (16 + q * 4 + (j - 4));
                    if (t < 12) v = W1[(((t - 4) & 1) * 32 + kp) * 64 + ((t - 4) >> 1) * 16 + n];
                    else        v = (n < 8) ? W2[((t - 12) * 32 + kp) * 8 + n] : 0.0f;
                }
                h2[s] = bf16_rn(v);
            }
            hi[d] = h2[0] | (h2[1] << 16);
        }
        ((uint4*)ws)[t * 64 + lane] = make_uint4(hi[0], hi[1], hi[2], hi[3]);
    }
}

template<bool BT>
__global__ __launch_bounds__(BLOCK, 4)
void ngp_mfma(const float*  __restrict__ xyz,
              const float2* __restrict__ tbl,
              const int*    __restrict__ boundp,
              const unsigned* __restrict__ wsw,
              float*        __restrict__ out,
              int ntiles)
{
    // LDS: x only. row = eval (16 dw = 32 bf16 feats), quad XOR-swizzled.
    __shared__ __align__(16) unsigned lds[4096];
    const int tid  = threadIdx.x;
    const int lane = tid & 63;
    const int wv   = tid >> 6;
    const int col  = lane & 15;
    const int q    = lane >> 4;

    // ---- weights -> registers, once per block (L2-broadcast, 14x16B/lane)
    short8_t w[14];
    {
        const short8_t* __restrict__ wfr = (const short8_t*)wsw;
        #pragma unroll
        for (int t = 0; t < 14; ++t) w[t] = wfr[t * 64 + lane];
    }

    const unsigned* __restrict__ tbx = wsw + TOFF;
    const float bnd = (float)boundp[0];
    const float sc  = 0.5f / bnd;
    const f32x4 zero = {0.0f, 0.0f, 0.0f, 0.0f};
    const int swz = (tid ^ (tid >> 2) ^ (tid >> 4)) & 3;

    #pragma unroll 1
    for (int it = 0; it < ITER; ++it) {
        const int tile = blockIdx.x * ITER + it;
        if (tile >= ntiles) break;

        // ================= encode =================
        const int ge = tile * BLOCK + tid;
        const int pt = ge >> 3;
        const int b  = ge & 7;

        const float cxf = (xyz[pt * 3 + 0] + bnd) * sc * 512.0f;
        const float cyf = (xyz[pt * 3 + 1] + bnd) * sc * 512.0f;
        const float czf = (xyz[pt * 3 + 2] + bnd) * sc * 512.0f;

        const float c0x = fminf(fmaxf(floorf(cxf), 0.0f), 511.0f);
        const float c0y = fminf(fmaxf(floorf(cyf), 0.0f), 511.0f);
        const float c0z = fminf(fmaxf(floorf(czf), 0.0f), 511.0f);
        const float frx = cxf - c0x;
        const float fry = cyf - c0y;
        const float frz = czf - c0z;

        const unsigned kx = (unsigned)c0x + (unsigned)(b & 1);
        const unsigned ky = (unsigned)c0y + (unsigned)((b >> 1) & 1);
        const unsigned kz = (unsigned)c0z + (unsigned)((b >> 2) & 1);

        const float wb = ((b & 1) ? frx : 1.0f - frx)
                       * ((b & 2) ? fry : 1.0f - fry)
                       * ((b & 4) ? frz : 1.0f - frz);

        // fine levels (l=5..15): frac==0, single gather each (compacted).
        const unsigned kyp = ky * cP1;
        const unsigned kzp = kz * cP2;
        const unsigned X   = kx ^ kyp ^ kzp;
        unsigned gfu[11];
        float2   gff[11];
        #pragma unroll
        for (int l = 5; l < 16; ++l) {
            const int s = l - 5;
            if (BT) {
                const unsigned base = (1u << 20) + ((1u << 20) - ((1u << 20) >> s));
                gfu[l - 5] = tbx[base + (X & (kMask >> s))];
            } else {
                const unsigned idx = ((kx << s) ^ (kyp << s) ^ (kzp << s)) & kMask;
                gff[l - 5] = tbl[(size_t)l * kT + idx];
            }
        }

        // hashed coarse (l=3,4): prefetch 16 gathers
        float2 gH[2][8];
        #pragma unroll
        for (int l = 3; l < 5; ++l) {
            const int d = 5 - l;
            const unsigned qx = kx >> d, qy = ky >> d, qz = kz >> d;
            const unsigned hy0 = qy * cP1, hy1 = hy0 + cP1;
            const unsigned hz0 = qz * cP2, hz1 = hz0 + cP2;
            const unsigned x1u = qx + 1u;
            unsigned hidx[8];
            hidx[0] = (qx  ^ hy0 ^ hz0) & kMask;  hidx[1] = (x1u ^ hy0 ^ hz0) & kMask;
            hidx[2] = (qx  ^ hy1 ^ hz0) & kMask;  hidx[3] = (x1u ^ hy1 ^ hz0) & kMask;
            hidx[4] = (qx  ^ hy0 ^ hz1) & kMask;  hidx[5] = (x1u ^ hy0 ^ hz1) & kMask;
            hidx[6] = (qx  ^ hy1 ^ hz1) & kMask;  hidx[7] = (x1u ^ hy1 ^ hz1) & kMask;
            if (BT) {
                const unsigned* __restrict__ base = tbx + (size_t)(l - 3) * kT;
                #pragma unroll
                for (int c = 0; c < 8; ++c) gH[l - 3][c] = bf2dec(base[hidx[c]]);
            } else {
                const float2* __restrict__ base = tbl + (size_t)l * kT;
                #pragma unroll
                for (int c = 0; c < 8; ++c) gH[l - 3][c] = base[hidx[c]];
            }
        }

        float2 gc[5];
        #pragma unroll
        for (int l = 0; l < 5; ++l) {
            const int d = 5 - l;
            const unsigned m = (1u << d) - 1u;
            const float inv = 1.0f / (float)(1 << d);
            const unsigned qx = kx >> d, qy = ky >> d, qz = kz >> d;
            const float fx = (float)(kx & m) * inv;
            const float fy = (float)(ky & m) * inv;
            const float fz = (float)(kz & m) * inv;
            float2 g0, g1, g2, g3, g4, g5, g6, g7;
            if (l < 3) {                     // dense fp32 (cache-resident), clamp
                const unsigned res = 16u << l;
                const unsigned R = res + 1u, R2 = R * R;
                const unsigned x0 = (qx < res ? qx : res);
                const unsigned x1 = (qx + 1u < res ? qx + 1u : res);
                const unsigned y0 = (qy < res ? qy : res) * R;
                const unsigned y1 = (qy + 1u < res ? qy + 1u : res) * R;
                const unsigned z0 = (qz < res ? qz : res) * R2;
                const unsigned z1 = (qz + 1u < res ? qz + 1u : res) * R2;
                const float2* __restrict__ base = tbl + (size_t)l * kT;
                g0 = base[x0 + y0 + z0]; g1 = base[x1 + y0 + z0];
                g2 = base[x0 + y1 + z0]; g3 = base[x1 + y1 + z0];
                g4 = base[x0 + y0 + z1]; g5 = base[x1 + y0 + z1];
                g6 = base[x0 + y1 + z1]; g7 = base[x1 + y1 + z1];
            } else {
                g0 = gH[l - 3][0]; g1 = gH[l - 3][1]; g2 = gH[l - 3][2]; g3 = gH[l - 3][3];
                g4 = gH[l - 3][4]; g5 = gH[l - 3][5]; g6 = gH[l - 3][6]; g7 = gH[l - 3][7];
            }
            const float wx1 = fx, wx0 = 1.0f - fx;
            const float wy1 = fy, wy0 = 1.0f - fy;
            const float wz1 = fz, wz0 = 1.0f - fz;
            const float w00 = wx0 * wy0, w10 = wx1 * wy0, w01 = wx0 * wy1, w11 = wx1 * wy1;
            const float a0 = w00 * wz0, a1 = w10 * wz0, a2 = w01 * wz0, a3 = w11 * wz0;
            const float a4 = w00 * wz1, a5 = w10 * wz1, a6 = w01 * wz1, a7 = w11 * wz1;
            float vx = a0 * g0.x + a1 * g1.x + a2 * g2.x + a3 * g3.x
                     + a4 * g4.x + a5 * g5.x + a6 * g6.x + a7 * g7.x;
            float vy = a0 * g0.y + a1 * g1.y + a2 * g2.y + a3 * g3.y
                     + a4 * g4.y + a5 * g5.y + a6 * g6.y + a7 * g7.y;
            gc[l] = make_float2(vx, vy);
        }

        // pack features: dword l = (bf16(f_{2l}), bf16(f_{2l+1}))
        unsigned xd[16];
        #pragma unroll
        for (int l = 0; l < 5; ++l)
            xd[l] = cvtpk(gc[l].x, gc[l].y);
        #pragma unroll
        for (int l = 5; l < 16; ++l) {
            if (BT) xd[l] = gfu[l - 5];
            else    xd[l] = cvtpk(gff[l - 5].x, gff[l - 5].y);
        }
        // swizzled x write: quad k at position k^swz (row = tid)
        {
            uint4* xrow = (uint4*)(lds + tid * 16);
            xrow[swz]     = make_uint4(xd[0],  xd[1],  xd[2],  xd[3]);
            xrow[swz ^ 1] = make_uint4(xd[4],  xd[5],  xd[6],  xd[7]);
            xrow[swz ^ 2] = make_uint4(xd[8],  xd[9],  xd[10], xd[11]);
            xrow[swz ^ 3] = make_uint4(xd[12], xd[13], xd[14], xd[15]);
        }

        // x exchange is within-wave (ev = wv*64+...) -> wave-local fence only
        asm volatile("s_waitcnt lgkmcnt(0)" ::: "memory");

        // ================= MLP (transposed MFMA, weights in regs) =========
        #pragma unroll 1
        for (int g = 0; g < 4; ++g) {
            const int ev  = wv * 64 + g * 16 + col;
            const int esw = ((ev ^ (ev >> 2) ^ (ev >> 4)) & 3) ^ q;
            const short8_t xb = *(const short8_t*)(lds + ev * 16 + esw * 4);
            const float wbv = __shfl(wb, g * 16 + col, 64);

            unsigned hp0[4], hp1[4];
            // layer 1
            #pragma unroll
            for (int mt = 0; mt < 4; ++mt) {
                f32x4 a = mfma16(w[mt], xb, zero);
                hp0[mt] = cvtpk(fmaxf(a[0], 0.0f), fmaxf(a[1], 0.0f));
                hp1[mt] = cvtpk(fmaxf(a[2], 0.0f), fmaxf(a[3], 0.0f));
            }
            uint4 u0 = make_uint4(hp0[0], hp1[0], hp0[1], hp1[1]);
            uint4 u1 = make_uint4(hp0[2], hp1[2], hp0[3], hp1[3]);
            short8_t bk0 = *(short8_t*)&u0;
            short8_t bk1 = *(short8_t*)&u1;

            // layer 2
            #pragma unroll
            for (int mt = 0; mt < 4; ++mt) {
                f32x4 a = mfma16(w[4 + mt * 2], bk0, zero);
                a = mfma16(w[5 + mt * 2], bk1, a);
                hp0[mt] = cvtpk(fmaxf(a[0], 0.0f), fmaxf(a[1], 0.0f));
                hp1[mt] = cvtpk(fmaxf(a[2], 0.0f), fmaxf(a[3], 0.0f));
            }
            u0 = make_uint4(hp0[0], hp1[0], hp0[1], hp1[1]);
            u1 = make_uint4(hp0[2], hp1[2], hp0[3], hp1[3]);
            bk0 = *(short8_t*)&u0;
            bk1 = *(short8_t*)&u1;

            // layer 3
            f32x4 a3 = mfma16(w[12], bk0, zero);
            a3 = mfma16(w[13], bk1, a3);

            // weight by wb and reduce over the 8 corners (eval low 3 bits)
            float v0 = wbv * a3[0], v1 = wbv * a3[1], v2 = wbv * a3[2], v3 = wbv * a3[3];
            #pragma unroll
            for (int s = 1; s < 8; s <<= 1) {
                v0 += __shfl_xor(v0, s);
                v1 += __shfl_xor(v1, s);
                v2 += __shfl_xor(v2, s);
                v3 += __shfl_xor(v3, s);
            }
            if (((lane & 7) == 0) && q < 2) {
                const int p = (tile * BLOCK + ev) >> 3;
                *(float4*)(out + p * 8 + q * 4) = make_float4(v0, v1, v2, v3);
            }
        }
    }
}

extern "C" void kernel_launch(void* const* d_in, const int* in_sizes, int n_in,
                              void* d_out, int out_size, void* d_ws, size_t ws_size,
                              hipStream_t stream) {
    const float*  xyz = (const float*)d_in[0];
    const float2* tbl = (const float2*)d_in[1];
    const float*  W0  = (const float*)d_in[2];
    const float*  W1  = (const float*)d_in[3];
    const float*  W2  = (const float*)d_in[4];
    const int*    bnd = (const int*)d_in[5];
    float* out = (float*)d_out;

    const int npts   = in_sizes[0] / 3;
    const int total  = npts * 8;
    const int ntiles = total / BLOCK;
    const int grid   = (ntiles + ITER - 1) / ITER;

    const bool big = (ws_size >= WS_NEED);
    const int ncc = big ? (1 << 19) / 256 : 0;                  // 2048
    const int ncf = big ? ((1 << 20) - (1 << 9)) / 256 : 0;     // 4094

    hipLaunchKernelGGL(prep_all, dim3(ncc + ncf + 4), dim3(256), 0, stream,
                       W0, W1, W2, tbl, (unsigned*)d_ws, ncc, ncf);

    if (big) {
        hipLaunchKernelGGL(ngp_mfma<true>, dim3(grid), dim3(BLOCK), 0, stream,
                           xyz, tbl, bnd, (const unsigned*)d_ws, out, ntiles);
    } else {
        hipLaunchKernelGGL(ngp_mfma<false>, dim3(grid), dim3(BLOCK), 0, stream,
                           xyz, tbl, bnd, (const unsigned*)d_ws, out, ntiles);
    }
}

// Round 2
// 227.659 us; speedup vs baseline: 1.1412x; 1.1412x over previous
//
#include <hip/hip_runtime.h>

// Instant-NGP hash encode (16 levels, F=2) + 32->64->64->8 MLP via MFMA,
// outer trilinear over 8 corners of a 512^3 grid.
//
// R11: compacted fine levels (8MB random region), FETCH 313MB, 136us.
// R12 FAILED (163us): w[14] in regs across encode+ITER loop => spill
//   (WRITE 8.7->64MB). Swizzle (conflicts 1.1e7->5e5) + cvtpk kept.
// R13: phase-split registers. Encode phase runs with no weights live;
//   memory-clobber fence + sched_barrier(0) pins the 14 weight-frag loads
//   AFTER encode => peak VGPR = max(phase) not sum. LDS = 16KB x only,
//   ZERO barriers (x-exchange is wave-local: ev = wv*64+g*16+col), so
//   waves never couple their gather stalls. ITER=1, grid 8192,
//   launch_bounds(256,5) -> 20 waves/CU target.

typedef __attribute__((ext_vector_type(8))) short short8_t;
typedef __attribute__((ext_vector_type(4))) float f32x4;

static constexpr unsigned kT    = 1u << 19;
static constexpr unsigned kMask = kT - 1u;
static constexpr unsigned cP1   = 2654435761u;
static constexpr unsigned cP2   = 805459861u;
static constexpr int      BLOCK = 256;
static constexpr int      TOFF  = 4096;    // d_ws dword offset of tables
static constexpr size_t   WS_NEED = ((size_t)TOFF + (1u << 21)) * 4;  // 16KB+8MB

static __device__ __forceinline__ unsigned bf16_rn(float x) {
    unsigned u = __float_as_uint(x);
    return (u + 0x7fffu + ((u >> 16) & 1u)) >> 16;   // round-to-nearest-even
}

static __device__ __forceinline__ float2 bf2dec(unsigned u) {
    return make_float2(__uint_as_float(u << 16),
                       __uint_as_float(u & 0xffff0000u));
}

// packed f32x2 -> bf16x2, RNE (bit-identical to bf16_rn pair). lo in low 16.
static __device__ __forceinline__ unsigned cvtpk(float lo, float hi) {
    unsigned r;
    asm("v_cvt_pk_bf16_f32 %0, %1, %2" : "=v"(r) : "v"(lo), "v"(hi));
    return r;
}

static __device__ __forceinline__ f32x4 mfma16(short8_t a, short8_t b, f32x4 c) {
    return __builtin_amdgcn_mfma_f32_16x16x32_bf16(a, b, c, 0, 0, 0);
}

// ---- fused prep: [0,ncc) coarse bf16 convert; [ncc,ncc+ncf) fine
// convert+compact; tail 4 blocks = weight pre-swizzle (14 tiles x 64 lanes).
__global__ __launch_bounds__(256)
void prep_all(const float* __restrict__ W0, const float* __restrict__ W1,
              const float* __restrict__ W2, const float2* __restrict__ tbl,
              unsigned* __restrict__ ws, int ncc, int ncf)
{
    const int bx = blockIdx.x, tid = threadIdx.x;
    if (bx < ncc) {
        // coarse levels 3,4: fp32x2 -> packed bf16x2 (pairs of entries)
        const int i = bx * 256 + tid;                // < 2^19
        const float4 v = ((const float4*)(tbl + (size_t)3 * kT))[i];
        ((uint2*)(ws + TOFF))[i] =
            make_uint2(bf16_rn(v.x) | (bf16_rn(v.y) << 16),
                       bf16_rn(v.z) | (bf16_rn(v.w) << 16));
    } else if (bx < ncc + ncf) {
        // fine level 5+s entry (j<<s) -> compact slot j at fineOff(s)
        const int i = (bx - ncc) * 256 + tid;        // < 2^20 - 2^9
        const unsigned vv = (1u << 20) - 1u - (unsigned)i;
        const int s = __clz((int)vv) - 12;           // 0..10
        const unsigned fo = (1u << 20) - ((1u << 20) >> s);
        const unsigned j = (unsigned)i - fo;
        const float2 e = tbl[((size_t)(5 + s) << 19) + ((size_t)j << s)];
        (ws + TOFF + (1u << 20))[i] = bf16_rn(e.x) | (bf16_rn(e.y) << 16);
    } else {
        // weights: A-frag order, bf16 RNE. tiles 0..3 = W0; 4..11 = W1
        // (mt=(t-4)>>1, kt=(t-4)&1, K pi-permuted); 12..13 = W2 (cols>=8 zero)
        const int t = (bx - ncc - ncf) * 4 + (tid >> 6);
        if (t >= 14) return;
        const int lane = tid & 63;
        const int n = lane & 15, q = lane >> 4;
        unsigned hi[4];
        #pragma unroll
        for (int d = 0; d < 4; ++d) {
            unsigned h2[2];
            #pragma unroll
            for (int s = 0; s < 2; ++s) {
                const int j = d * 2 + s;
                float v;
                if (t < 4) {
                    v = W0[(q * 8 + j) * 64 + t * 16 + n];
                } else {
                    const int kp = (j < 4) ? (q * 4 + j) : (16 + q * 4 + (j - 4));
                    if (t < 12) v = W1[(((t - 4) & 1) * 32 + kp) * 64 + ((t - 4) >> 1) * 16 + n];
                    else        v = (n < 8) ? W2[((t - 12) * 32 + kp) * 8 + n] : 0.0f;
                }
                h2[s] = bf16_rn(v);
            }
            hi[d] = h2[0] | (h2[1] << 16);
        }
        ((uint4*)ws)[t * 64 + lane] = make_uint4(hi[0], hi[1], hi[2], hi[3]);
    }
}

template<bool BT>
__global__ __launch_bounds__(BLOCK, 5)
void ngp_mfma(const float*  __restrict__ xyz,
              const float2* __restrict__ tbl,
              const int*    __restrict__ boundp,
              const unsigned* __restrict__ wsw,
              float*        __restrict__ out,
              int ntiles)
{
    // LDS: x only. row = eval (16 dw = 32 bf16 feats), quad XOR-swizzled.
    __shared__ __align__(16) unsigned lds[4096];
    const int tid  = threadIdx.x;
    const int lane = tid & 63;
    const int wv   = tid >> 6;
    const int col  = lane & 15;
    const int q    = lane >> 4;
    const int swz  = (tid ^ (tid >> 2) ^ (tid >> 4)) & 3;

    const unsigned* __restrict__ tbx = wsw + TOFF;
    const float bnd = (float)boundp[0];
    const float sc  = 0.5f / bnd;
    const f32x4 zero = {0.0f, 0.0f, 0.0f, 0.0f};

    // ================= encode (no weights live) =================
    const int ge = blockIdx.x * BLOCK + tid;
    const int pt = ge >> 3;
    const int b  = ge & 7;

    const float cxf = (xyz[pt * 3 + 0] + bnd) * sc * 512.0f;
    const float cyf = (xyz[pt * 3 + 1] + bnd) * sc * 512.0f;
    const float czf = (xyz[pt * 3 + 2] + bnd) * sc * 512.0f;

    const float c0x = fminf(fmaxf(floorf(cxf), 0.0f), 511.0f);
    const float c0y = fminf(fmaxf(floorf(cyf), 0.0f), 511.0f);
    const float c0z = fminf(fmaxf(floorf(czf), 0.0f), 511.0f);
    const float frx = cxf - c0x;
    const float fry = cyf - c0y;
    const float frz = czf - c0z;

    const unsigned kx = (unsigned)c0x + (unsigned)(b & 1);
    const unsigned ky = (unsigned)c0y + (unsigned)((b >> 1) & 1);
    const unsigned kz = (unsigned)c0z + (unsigned)((b >> 2) & 1);

    const float wb = ((b & 1) ? frx : 1.0f - frx)
                   * ((b & 2) ? fry : 1.0f - fry)
                   * ((b & 4) ? frz : 1.0f - frz);

    // fine levels (l=5..15): frac==0, single gather each (compacted).
    const unsigned kyp = ky * cP1;
    const unsigned kzp = kz * cP2;
    const unsigned X   = kx ^ kyp ^ kzp;
    unsigned gfu[11];
    float2   gff[11];
    #pragma unroll
    for (int l = 5; l < 16; ++l) {
        const int s = l - 5;
        if (BT) {
            const unsigned base = (1u << 20) + ((1u << 20) - ((1u << 20) >> s));
            gfu[l - 5] = tbx[base + (X & (kMask >> s))];
        } else {
            const unsigned idx = ((kx << s) ^ (kyp << s) ^ (kzp << s)) & kMask;
            gff[l - 5] = tbl[(size_t)l * kT + idx];
        }
    }

    // hashed coarse (l=3,4): prefetch 16 gathers (raw u32 in BT: decode at use)
    unsigned gH[2][8];
    float2   gHf[2][8];
    #pragma unroll
    for (int l = 3; l < 5; ++l) {
        const int d = 5 - l;
        const unsigned qx = kx >> d, qy = ky >> d, qz = kz >> d;
        const unsigned hy0 = qy * cP1, hy1 = hy0 + cP1;
        const unsigned hz0 = qz * cP2, hz1 = hz0 + cP2;
        const unsigned x1u = qx + 1u;
        unsigned hidx[8];
        hidx[0] = (qx  ^ hy0 ^ hz0) & kMask;  hidx[1] = (x1u ^ hy0 ^ hz0) & kMask;
        hidx[2] = (qx  ^ hy1 ^ hz0) & kMask;  hidx[3] = (x1u ^ hy1 ^ hz0) & kMask;
        hidx[4] = (qx  ^ hy0 ^ hz1) & kMask;  hidx[5] = (x1u ^ hy0 ^ hz1) & kMask;
        hidx[6] = (qx  ^ hy1 ^ hz1) & kMask;  hidx[7] = (x1u ^ hy1 ^ hz1) & kMask;
        if (BT) {
            const unsigned* __restrict__ base = tbx + (size_t)(l - 3) * kT;
            #pragma unroll
            for (int c = 0; c < 8; ++c) gH[l - 3][c] = base[hidx[c]];
        } else {
            const float2* __restrict__ base = tbl + (size_t)l * kT;
            #pragma unroll
            for (int c = 0; c < 8; ++c) gHf[l - 3][c] = base[hidx[c]];
        }
    }

    float2 gc[5];
    #pragma unroll
    for (int l = 0; l < 5; ++l) {
        const int d = 5 - l;
        const unsigned m = (1u << d) - 1u;
        const float inv = 1.0f / (float)(1 << d);
        const unsigned qx = kx >> d, qy = ky >> d, qz = kz >> d;
        const float fx = (float)(kx & m) * inv;
        const float fy = (float)(ky & m) * inv;
        const float fz = (float)(kz & m) * inv;
        float2 g0, g1, g2, g3, g4, g5, g6, g7;
        if (l < 3) {                     // dense fp32 (cache-resident), clamp
            const unsigned res = 16u << l;
            const unsigned R = res + 1u, R2 = R * R;
            const unsigned x0 = (qx < res ? qx : res);
            const unsigned x1 = (qx + 1u < res ? qx + 1u : res);
            const unsigned y0 = (qy < res ? qy : res) * R;
            const unsigned y1 = (qy + 1u < res ? qy + 1u : res) * R;
            const unsigned z0 = (qz < res ? qz : res) * R2;
            const unsigned z1 = (qz + 1u < res ? qz + 1u : res) * R2;
            const float2* __restrict__ base = tbl + (size_t)l * kT;
            g0 = base[x0 + y0 + z0]; g1 = base[x1 + y0 + z0];
            g2 = base[x0 + y1 + z0]; g3 = base[x1 + y1 + z0];
            g4 = base[x0 + y0 + z1]; g5 = base[x1 + y0 + z1];
            g6 = base[x0 + y1 + z1]; g7 = base[x1 + y1 + z1];
        } else if (BT) {
            g0 = bf2dec(gH[l - 3][0]); g1 = bf2dec(gH[l - 3][1]);
            g2 = bf2dec(gH[l - 3][2]); g3 = bf2dec(gH[l - 3][3]);
            g4 = bf2dec(gH[l - 3][4]); g5 = bf2dec(gH[l - 3][5]);
            g6 = bf2dec(gH[l - 3][6]); g7 = bf2dec(gH[l - 3][7]);
        } else {
            g0 = gHf[l - 3][0]; g1 = gHf[l - 3][1]; g2 = gHf[l - 3][2]; g3 = gHf[l - 3][3];
            g4 = gHf[l - 3][4]; g5 = gHf[l - 3][5]; g6 = gHf[l - 3][6]; g7 = gHf[l - 3][7];
        }
        const float wx1 = fx, wx0 = 1.0f - fx;
        const float wy1 = fy, wy0 = 1.0f - fy;
        const float wz1 = fz, wz0 = 1.0f - fz;
        const float w00 = wx0 * wy0, w10 = wx1 * wy0, w01 = wx0 * wy1, w11 = wx1 * wy1;
        const float a0 = w00 * wz0, a1 = w10 * wz0, a2 = w01 * wz0, a3 = w11 * wz0;
        const float a4 = w00 * wz1, a5 = w10 * wz1, a6 = w01 * wz1, a7 = w11 * wz1;
        float vx = a0 * g0.x + a1 * g1.x + a2 * g2.x + a3 * g3.x
                 + a4 * g4.x + a5 * g5.x + a6 * g6.x + a7 * g7.x;
        float vy = a0 * g0.y + a1 * g1.y + a2 * g2.y + a3 * g3.y
                 + a4 * g4.y + a5 * g5.y + a6 * g6.y + a7 * g7.y;
        gc[l] = make_float2(vx, vy);
    }

    // pack features: dword l = (bf16(f_{2l}), bf16(f_{2l+1}))
    unsigned xd[16];
    #pragma unroll
    for (int l = 0; l < 5; ++l)
        xd[l] = cvtpk(gc[l].x, gc[l].y);
    #pragma unroll
    for (int l = 5; l < 16; ++l) {
        if (BT) xd[l] = gfu[l - 5];
        else    xd[l] = cvtpk(gff[l - 5].x, gff[l - 5].y);
    }
    // swizzled x write: quad k at position k^swz (row = tid)
    {
        uint4* xrow = (uint4*)(lds + tid * 16);
        xrow[swz]     = make_uint4(xd[0],  xd[1],  xd[2],  xd[3]);
        xrow[swz ^ 1] = make_uint4(xd[4],  xd[5],  xd[6],  xd[7]);
        xrow[swz ^ 2] = make_uint4(xd[8],  xd[9],  xd[10], xd[11]);
        xrow[swz ^ 3] = make_uint4(xd[12], xd[13], xd[14], xd[15]);
    }

    // x exchange is within-wave (ev = wv*64+...) -> wave-local fence only.
    // The memory clobber also pins the weight loads BELOW this point
    // (phase split: encode pressure and w[14] never coexist).
    asm volatile("s_waitcnt lgkmcnt(0)" ::: "memory");
    __builtin_amdgcn_sched_barrier(0);

    // ---- weights -> 56 VGPRs (same addresses all waves: L1/L2 broadcast)
    short8_t w[14];
    {
        const short8_t* __restrict__ wfr = (const short8_t*)wsw;
        #pragma unroll
        for (int t = 0; t < 14; ++t) w[t] = wfr[t * 64 + lane];
    }

    // ================= MLP (transposed MFMA, weights in regs) =========
    #pragma unroll 1
    for (int g = 0; g < 4; ++g) {
        const int ev  = wv * 64 + g * 16 + col;
        const int esw = ((ev ^ (ev >> 2) ^ (ev >> 4)) & 3) ^ q;
        const short8_t xb = *(const short8_t*)(lds + ev * 16 + esw * 4);
        const float wbv = __shfl(wb, g * 16 + col, 64);

        unsigned hp0[4], hp1[4];
        // layer 1
        #pragma unroll
        for (int mt = 0; mt < 4; ++mt) {
            f32x4 a = mfma16(w[mt], xb, zero);
            hp0[mt] = cvtpk(fmaxf(a[0], 0.0f), fmaxf(a[1], 0.0f));
            hp1[mt] = cvtpk(fmaxf(a[2], 0.0f), fmaxf(a[3], 0.0f));
        }
        uint4 u0 = make_uint4(hp0[0], hp1[0], hp0[1], hp1[1]);
        uint4 u1 = make_uint4(hp0[2], hp1[2], hp0[3], hp1[3]);
        short8_t bk0 = *(short8_t*)&u0;
        short8_t bk1 = *(short8_t*)&u1;

        // layer 2
        #pragma unroll
        for (int mt = 0; mt < 4; ++mt) {
            f32x4 a = mfma16(w[4 + mt * 2], bk0, zero);
            a = mfma16(w[5 + mt * 2], bk1, a);
            hp0[mt] = cvtpk(fmaxf(a[0], 0.0f), fmaxf(a[1], 0.0f));
            hp1[mt] = cvtpk(fmaxf(a[2], 0.0f), fmaxf(a[3], 0.0f));
        }
        u0 = make_uint4(hp0[0], hp1[0], hp0[1], hp1[1]);
        u1 = make_uint4(hp0[2], hp1[2], hp0[3], hp1[3]);
        bk0 = *(short8_t*)&u0;
        bk1 = *(short8_t*)&u1;

        // layer 3
        f32x4 a3 = mfma16(w[12], bk0, zero);
        a3 = mfma16(w[13], bk1, a3);

        // weight by wb and reduce over the 8 corners (eval low 3 bits)
        float v0 = wbv * a3[0], v1 = wbv * a3[1], v2 = wbv * a3[2], v3 = wbv * a3[3];
        #pragma unroll
        for (int s = 1; s < 8; s <<= 1) {
            v0 += __shfl_xor(v0, s);
            v1 += __shfl_xor(v1, s);
            v2 += __shfl_xor(v2, s);
            v3 += __shfl_xor(v3, s);
        }
        if (((lane & 7) == 0) && q < 2) {
            const int p = (blockIdx.x * BLOCK + ev) >> 3;
            *(float4*)(out + p * 8 + q * 4) = make_float4(v0, v1, v2, v3);
        }
    }
}

extern "C" void kernel_launch(void* const* d_in, const int* in_sizes, int n_in,
                              void* d_out, int out_size, void* d_ws, size_t ws_size,
                              hipStream_t stream) {
    const float*  xyz = (const float*)d_in[0];
    const float2* tbl = (const float2*)d_in[1];
    const float*  W0  = (const float*)d_in[2];
    const float*  W1  = (const float*)d_in[3];
    const float*  W2  = (const float*)d_in[4];
    const int*    bnd = (const int*)d_in[5];
    float* out = (float*)d_out;

    const int npts   = in_sizes[0] / 3;
    const int total  = npts * 8;
    const int ntiles = total / BLOCK;
    const int grid   = ntiles;

    const bool big = (ws_size >= WS_NEED);
    const int ncc = big ? (1 << 19) / 256 : 0;                  // 2048
    const int ncf = big ? ((1 << 20) - (1 << 9)) / 256 : 0;     // 4094

    hipLaunchKernelGGL(prep_all, dim3(ncc + ncf + 4), dim3(256), 0, stream,
                       W0, W1, W2, tbl, (unsigned*)d_ws, ncc, ncf);

    if (big) {
        hipLaunchKernelGGL(ngp_mfma<true>, dim3(grid), dim3(BLOCK), 0, stream,
                           xyz, tbl, bnd, (const unsigned*)d_ws, out, ntiles);
    } else {
        hipLaunchKernelGGL(ngp_mfma<false>, dim3(grid), dim3(BLOCK), 0, stream,
                           xyz, tbl, bnd, (const unsigned*)d_ws, out, ntiles);
    }
}

// Round 3
// 214.467 us; speedup vs baseline: 1.2114x; 1.0615x over previous
//
#include <hip/hip_runtime.h>

// Instant-NGP hash encode (16 levels, F=2) + 32->64->64->8 MLP via MFMA,
// outer trilinear over 8 corners of a 512^3 grid.
//
// R11: compacted fine levels, FETCH 313MB, 136us.
// R12 FAILED: reg spill. Swizzle + cvtpk kept.
// R13: phase-split regs, zero barriers, 133us. Law: dur tracks FETCH at
//   ~2.35 TB/s (L2-miss path). Hot random footprint 7.5MB vs 4MB per-XCD
//   L2 => ~45% capacity misses = 250MB of the 312MB FETCH.
// R14: two-pass level split so each pass's random footprint fits per-XCD L2.
//   Pass A: coarse L3+L4 (exactly 4MB, ~500 touches/line) -> partial bf16
//   features to d_ws (16MB streaming). Pass B: dense (bf16, 1.26MB) + fine
//   (4MB) + partial + MLP (hot ~5.3MB). Bit-identical partials; dense now
//   bf16 like all other levels.

typedef __attribute__((ext_vector_type(8))) short short8_t;
typedef __attribute__((ext_vector_type(4))) float f32x4;

static constexpr unsigned kT    = 1u << 19;
static constexpr unsigned kMask = kT - 1u;
static constexpr unsigned cP1   = 2654435761u;
static constexpr unsigned cP2   = 805459861u;
static constexpr int      BLOCK = 256;
static constexpr int      TOFF  = 4096;        // d_ws dword offset of tables
static constexpr unsigned DOFF  = 1u << 21;    // dense base within tbx (dwords)
static constexpr unsigned DN0   = 4913;        // 17^3
static constexpr unsigned DN1   = 40850;       // +33^3
static constexpr unsigned DENSE_N = 315475;    // +65^3
static constexpr unsigned PARTO = 2621440u;    // dword offset of partials (10MB)
static constexpr size_t   WS_NEED  = ((size_t)TOFF + (1u << 21)) * 4;      // 8MB+
static constexpr size_t   WS_NEED2 = ((size_t)PARTO + (1u << 22)) * 4;     // 26MB+

static __device__ __forceinline__ unsigned bf16_rn(float x) {
    unsigned u = __float_as_uint(x);
    return (u + 0x7fffu + ((u >> 16) & 1u)) >> 16;   // round-to-nearest-even
}

static __device__ __forceinline__ float2 bf2dec(unsigned u) {
    return make_float2(__uint_as_float(u << 16),
                       __uint_as_float(u & 0xffff0000u));
}

// packed f32x2 -> bf16x2, RNE (bit-identical to bf16_rn pair). lo in low 16.
static __device__ __forceinline__ unsigned cvtpk(float lo, float hi) {
    unsigned r;
    asm("v_cvt_pk_bf16_f32 %0, %1, %2" : "=v"(r) : "v"(lo), "v"(hi));
    return r;
}

static __device__ __forceinline__ f32x4 mfma16(short8_t a, short8_t b, f32x4 c) {
    return __builtin_amdgcn_mfma_f32_16x16x32_bf16(a, b, c, 0, 0, 0);
}

// ---- fused prep: [0,ncc) coarse bf16; [ncc,+ncf) fine compact; [+,+ncd)
// dense bf16; tail 4 blocks = weight pre-swizzle (14 tiles x 64 lanes).
__global__ __launch_bounds__(256)
void prep_all(const float* __restrict__ W0, const float* __restrict__ W1,
              const float* __restrict__ W2, const float2* __restrict__ tbl,
              unsigned* __restrict__ ws, int ncc, int ncf, int ncd)
{
    const int bx = blockIdx.x, tid = threadIdx.x;
    if (bx < ncc) {
        // coarse levels 3,4: fp32x2 -> packed bf16x2 (pairs of entries)
        const int i = bx * 256 + tid;                // < 2^19
        const float4 v = ((const float4*)(tbl + (size_t)3 * kT))[i];
        ((uint2*)(ws + TOFF))[i] =
            make_uint2(bf16_rn(v.x) | (bf16_rn(v.y) << 16),
                       bf16_rn(v.z) | (bf16_rn(v.w) << 16));
    } else if (bx < ncc + ncf) {
        // fine level 5+s entry (j<<s) -> compact slot j at fineOff(s)
        const int i = (bx - ncc) * 256 + tid;        // < 2^20 - 2^9
        const unsigned vv = (1u << 20) - 1u - (unsigned)i;
        const int s = __clz((int)vv) - 12;           // 0..10
        const unsigned fo = (1u << 20) - ((1u << 20) >> s);
        const unsigned j = (unsigned)i - fo;
        const float2 e = tbl[((size_t)(5 + s) << 19) + ((size_t)j << s)];
        (ws + TOFF + (1u << 20))[i] = bf16_rn(e.x) | (bf16_rn(e.y) << 16);
    } else if (bx < ncc + ncf + ncd) {
        // dense levels 0..2: fp32x2 -> bf16x2, packed contiguously
        const int i = (bx - ncc - ncf) * 256 + tid;
        if (i < (int)DENSE_N) {
            int l, off;
            if (i < (int)DN0)      { l = 0; off = i; }
            else if (i < (int)DN1) { l = 1; off = i - (int)DN0; }
            else                   { l = 2; off = i - (int)DN1; }
            const float2 e = tbl[(size_t)l * kT + off];
            ws[TOFF + DOFF + i] = bf16_rn(e.x) | (bf16_rn(e.y) << 16);
        }
    } else {
        // weights: A-frag order, bf16 RNE. tiles 0..3 = W0; 4..11 = W1
        // (mt=(t-4)>>1, kt=(t-4)&1, K pi-permuted); 12..13 = W2 (cols>=8 zero)
        const int t = (bx - ncc - ncf - ncd) * 4 + (tid >> 6);
        if (t >= 14) return;
        const int lane = tid & 63;
        const int n = lane & 15, q = lane >> 4;
        unsigned hi[4];
        #pragma unroll
        for (int d = 0; d < 4; ++d) {
            unsigned h2[2];
            #pragma unroll
            for (int s = 0; s < 2; ++s) {
                const int j = d * 2 + s;
                float v;
                if (t < 4) {
                    v = W0[(q * 8 + j) * 64 + t * 16 + n];
                } else {
                    const int kp = (j < 4) ? (q * 4 + j) : (16 + q * 4 + (j - 4));
                    if (t < 12) v = W1[(((t - 4) & 1) * 32 + kp) * 64 + ((t - 4) >> 1) * 16 + n];
                    else        v = (n < 8) ? W2[((t - 12) * 32 + kp) * 8 + n] : 0.0f;
                }
                h2[s] = bf16_rn(v);
            }
            hi[d] = h2[0] | (h2[1] << 16);
        }
        ((uint4*)ws)[t * 64 + lane] = make_uint4(hi[0], hi[1], hi[2], hi[3]);
    }
}

// ---- pass A: coarse levels 3,4 only (4MB working set = per-XCD L2).
// Writes packed bf16 partial features (bit-identical to R13's xd[3],xd[4]).
__global__ __launch_bounds__(256, 8)
void ngp_pa(const float* __restrict__ xyz, const int* __restrict__ boundp,
            unsigned* __restrict__ ws)
{
    const int tid = threadIdx.x;
    const int ge  = blockIdx.x * 256 + tid;
    const int pt  = ge >> 3;
    const int b   = ge & 7;

    const float bnd = (float)boundp[0];
    const float sc  = 0.5f / bnd;
    const float cxf = (xyz[pt * 3 + 0] + bnd) * sc * 512.0f;
    const float cyf = (xyz[pt * 3 + 1] + bnd) * sc * 512.0f;
    const float czf = (xyz[pt * 3 + 2] + bnd) * sc * 512.0f;
    const float c0x = fminf(fmaxf(floorf(cxf), 0.0f), 511.0f);
    const float c0y = fminf(fmaxf(floorf(cyf), 0.0f), 511.0f);
    const float c0z = fminf(fmaxf(floorf(czf), 0.0f), 511.0f);
    const unsigned kx = (unsigned)c0x + (unsigned)(b & 1);
    const unsigned ky = (unsigned)c0y + (unsigned)((b >> 1) & 1);
    const unsigned kz = (unsigned)c0z + (unsigned)((b >> 2) & 1);

    const unsigned* __restrict__ tbx = ws + TOFF;
    unsigned gH[2][8];
    #pragma unroll
    for (int l = 3; l < 5; ++l) {
        const int d = 5 - l;
        const unsigned qx = kx >> d, qy = ky >> d, qz = kz >> d;
        const unsigned hy0 = qy * cP1, hy1 = hy0 + cP1;
        const unsigned hz0 = qz * cP2, hz1 = hz0 + cP2;
        const unsigned x1u = qx + 1u;
        unsigned hidx[8];
        hidx[0] = (qx  ^ hy0 ^ hz0) & kMask;  hidx[1] = (x1u ^ hy0 ^ hz0) & kMask;
        hidx[2] = (qx  ^ hy1 ^ hz0) & kMask;  hidx[3] = (x1u ^ hy1 ^ hz0) & kMask;
        hidx[4] = (qx  ^ hy0 ^ hz1) & kMask;  hidx[5] = (x1u ^ hy0 ^ hz1) & kMask;
        hidx[6] = (qx  ^ hy1 ^ hz1) & kMask;  hidx[7] = (x1u ^ hy1 ^ hz1) & kMask;
        const unsigned* __restrict__ base = tbx + (size_t)(l - 3) * kT;
        #pragma unroll
        for (int c = 0; c < 8; ++c) gH[l - 3][c] = base[hidx[c]];
    }

    unsigned xd34[2];
    #pragma unroll
    for (int l = 3; l < 5; ++l) {
        const int d = 5 - l;
        const unsigned m = (1u << d) - 1u;
        const float inv = 1.0f / (float)(1 << d);
        const float fx = (float)(kx & m) * inv;
        const float fy = (float)(ky & m) * inv;
        const float fz = (float)(kz & m) * inv;
        const float2 g0 = bf2dec(gH[l - 3][0]), g1 = bf2dec(gH[l - 3][1]);
        const float2 g2 = bf2dec(gH[l - 3][2]), g3 = bf2dec(gH[l - 3][3]);
        const float2 g4 = bf2dec(gH[l - 3][4]), g5 = bf2dec(gH[l - 3][5]);
        const float2 g6 = bf2dec(gH[l - 3][6]), g7 = bf2dec(gH[l - 3][7]);
        const float wx1 = fx, wx0 = 1.0f - fx;
        const float wy1 = fy, wy0 = 1.0f - fy;
        const float wz1 = fz, wz0 = 1.0f - fz;
        const float w00 = wx0 * wy0, w10 = wx1 * wy0, w01 = wx0 * wy1, w11 = wx1 * wy1;
        const float a0 = w00 * wz0, a1 = w10 * wz0, a2 = w01 * wz0, a3 = w11 * wz0;
        const float a4 = w00 * wz1, a5 = w10 * wz1, a6 = w01 * wz1, a7 = w11 * wz1;
        const float vx = a0 * g0.x + a1 * g1.x + a2 * g2.x + a3 * g3.x
                       + a4 * g4.x + a5 * g5.x + a6 * g6.x + a7 * g7.x;
        const float vy = a0 * g0.y + a1 * g1.y + a2 * g2.y + a3 * g3.y
                       + a4 * g4.y + a5 * g5.y + a6 * g6.y + a7 * g7.y;
        xd34[l - 3] = cvtpk(vx, vy);
    }
    ((uint2*)(ws + PARTO))[ge] = make_uint2(xd34[0], xd34[1]);
}

// ---- pass B: dense (bf16) + fine + partial + MLP. Hot ~5.3MB.
__global__ __launch_bounds__(BLOCK, 5)
void ngp_pb(const float*  __restrict__ xyz,
            const int*    __restrict__ boundp,
            const unsigned* __restrict__ wsw,
            float*        __restrict__ out)
{
    // LDS: x only. row = eval (16 dw = 32 bf16 feats), quad XOR-swizzled.
    __shared__ __align__(16) unsigned lds[4096];
    const int tid  = threadIdx.x;
    const int lane = tid & 63;
    const int wv   = tid >> 6;
    const int col  = lane & 15;
    const int q    = lane >> 4;
    const int swz  = (tid ^ (tid >> 2) ^ (tid >> 4)) & 3;

    const unsigned* __restrict__ tbx = wsw + TOFF;
    const float bnd = (float)boundp[0];
    const float sc  = 0.5f / bnd;
    const f32x4 zero = {0.0f, 0.0f, 0.0f, 0.0f};

    // ================= encode (no weights live) =================
    const int ge = blockIdx.x * BLOCK + tid;
    const int pt = ge >> 3;
    const int b  = ge & 7;

    const float cxf = (xyz[pt * 3 + 0] + bnd) * sc * 512.0f;
    const float cyf = (xyz[pt * 3 + 1] + bnd) * sc * 512.0f;
    const float czf = (xyz[pt * 3 + 2] + bnd) * sc * 512.0f;
    const float c0x = fminf(fmaxf(floorf(cxf), 0.0f), 511.0f);
    const float c0y = fminf(fmaxf(floorf(cyf), 0.0f), 511.0f);
    const float c0z = fminf(fmaxf(floorf(czf), 0.0f), 511.0f);
    const float frx = cxf - c0x;
    const float fry = cyf - c0y;
    const float frz = czf - c0z;

    const unsigned kx = (unsigned)c0x + (unsigned)(b & 1);
    const unsigned ky = (unsigned)c0y + (unsigned)((b >> 1) & 1);
    const unsigned kz = (unsigned)c0z + (unsigned)((b >> 2) & 1);

    const float wb = ((b & 1) ? frx : 1.0f - frx)
                   * ((b & 2) ? fry : 1.0f - fry)
                   * ((b & 4) ? frz : 1.0f - frz);

    // fine levels (l=5..15): frac==0, single gather each (compacted).
    const unsigned kyp = ky * cP1;
    const unsigned kzp = kz * cP2;
    const unsigned X   = kx ^ kyp ^ kzp;
    unsigned gfu[11];
    #pragma unroll
    for (int l = 5; l < 16; ++l) {
        const int s = l - 5;
        const unsigned base = (1u << 20) + ((1u << 20) - ((1u << 20) >> s));
        gfu[l - 5] = tbx[base + (X & (kMask >> s))];
    }

    // coarse partial (written by pass A): streaming read
    const uint2 p34 = ((const uint2*)(wsw + PARTO))[ge];

    // dense levels 0..2 from bf16 tables in ws
    unsigned xd[16];
    #pragma unroll
    for (int l = 0; l < 3; ++l) {
        const int d = 5 - l;
        const unsigned m = (1u << d) - 1u;
        const float inv = 1.0f / (float)(1 << d);
        const unsigned qx = kx >> d, qy = ky >> d, qz = kz >> d;
        const float fx = (float)(kx & m) * inv;
        const float fy = (float)(ky & m) * inv;
        const float fz = (float)(kz & m) * inv;
        const unsigned res = 16u << l;
        const unsigned R = res + 1u, R2 = R * R;
        const unsigned x0 = (qx < res ? qx : res);
        const unsigned x1 = (qx + 1u < res ? qx + 1u : res);
        const unsigned y0 = (qy < res ? qy : res) * R;
        const unsigned y1 = (qy + 1u < res ? qy + 1u : res) * R;
        const unsigned z0 = (qz < res ? qz : res) * R2;
        const unsigned z1 = (qz + 1u < res ? qz + 1u : res) * R2;
        const unsigned dbase = DOFF + (l == 0 ? 0u : (l == 1 ? DN0 : DN1));
        const unsigned* __restrict__ base = tbx + dbase;
        const float2 g0 = bf2dec(base[x0 + y0 + z0]), g1 = bf2dec(base[x1 + y0 + z0]);
        const float2 g2 = bf2dec(base[x0 + y1 + z0]), g3 = bf2dec(base[x1 + y1 + z0]);
        const float2 g4 = bf2dec(base[x0 + y0 + z1]), g5 = bf2dec(base[x1 + y0 + z1]);
        const float2 g6 = bf2dec(base[x0 + y1 + z1]), g7 = bf2dec(base[x1 + y1 + z1]);
        const float wx1 = fx, wx0 = 1.0f - fx;
        const float wy1 = fy, wy0 = 1.0f - fy;
        const float wz1 = fz, wz0 = 1.0f - fz;
        const float w00 = wx0 * wy0, w10 = wx1 * wy0, w01 = wx0 * wy1, w11 = wx1 * wy1;
        const float a0 = w00 * wz0, a1 = w10 * wz0, a2 = w01 * wz0, a3 = w11 * wz0;
        const float a4 = w00 * wz1, a5 = w10 * wz1, a6 = w01 * wz1, a7 = w11 * wz1;
        const float vx = a0 * g0.x + a1 * g1.x + a2 * g2.x + a3 * g3.x
                       + a4 * g4.x + a5 * g5.x + a6 * g6.x + a7 * g7.x;
        const float vy = a0 * g0.y + a1 * g1.y + a2 * g2.y + a3 * g3.y
                       + a4 * g4.y + a5 * g5.y + a6 * g6.y + a7 * g7.y;
        xd[l] = cvtpk(vx, vy);
    }
    xd[3] = p34.x;
    xd[4] = p34.y;
    #pragma unroll
    for (int l = 5; l < 16; ++l) xd[l] = gfu[l - 5];

    // swizzled x write: quad k at position k^swz (row = tid)
    {
        uint4* xrow = (uint4*)(lds + tid * 16);
        xrow[swz]     = make_uint4(xd[0],  xd[1],  xd[2],  xd[3]);
        xrow[swz ^ 1] = make_uint4(xd[4],  xd[5],  xd[6],  xd[7]);
        xrow[swz ^ 2] = make_uint4(xd[8],  xd[9],  xd[10], xd[11]);
        xrow[swz ^ 3] = make_uint4(xd[12], xd[13], xd[14], xd[15]);
    }

    // x exchange is within-wave (ev = wv*64+...) -> wave-local fence only.
    // Memory clobber pins the weight loads below (phase-split pressure).
    asm volatile("s_waitcnt lgkmcnt(0)" ::: "memory");
    __builtin_amdgcn_sched_barrier(0);

    // ---- weights -> 56 VGPRs (same addresses all waves: L1/L2 broadcast)
    short8_t w[14];
    {
        const short8_t* __restrict__ wfr = (const short8_t*)wsw;
        #pragma unroll
        for (int t = 0; t < 14; ++t) w[t] = wfr[t * 64 + lane];
    }

    // ================= MLP (transposed MFMA, weights in regs) =========
    #pragma unroll 1
    for (int g = 0; g < 4; ++g) {
        const int ev  = wv * 64 + g * 16 + col;
        const int esw = ((ev ^ (ev >> 2) ^ (ev >> 4)) & 3) ^ q;
        const short8_t xb = *(const short8_t*)(lds + ev * 16 + esw * 4);
        const float wbv = __shfl(wb, g * 16 + col, 64);

        unsigned hp0[4], hp1[4];
        // layer 1
        #pragma unroll
        for (int mt = 0; mt < 4; ++mt) {
            f32x4 a = mfma16(w[mt], xb, zero);
            hp0[mt] = cvtpk(fmaxf(a[0], 0.0f), fmaxf(a[1], 0.0f));
            hp1[mt] = cvtpk(fmaxf(a[2], 0.0f), fmaxf(a[3], 0.0f));
        }
        uint4 u0 = make_uint4(hp0[0], hp1[0], hp0[1], hp1[1]);
        uint4 u1 = make_uint4(hp0[2], hp1[2], hp0[3], hp1[3]);
        short8_t bk0 = *(short8_t*)&u0;
        short8_t bk1 = *(short8_t*)&u1;

        // layer 2
        #pragma unroll
        for (int mt = 0; mt < 4; ++mt) {
            f32x4 a = mfma16(w[4 + mt * 2], bk0, zero);
            a = mfma16(w[5 + mt * 2], bk1, a);
            hp0[mt] = cvtpk(fmaxf(a[0], 0.0f), fmaxf(a[1], 0.0f));
            hp1[mt] = cvtpk(fmaxf(a[2], 0.0f), fmaxf(a[3], 0.0f));
        }
        u0 = make_uint4(hp0[0], hp1[0], hp0[1], hp1[1]);
        u1 = make_uint4(hp0[2], hp1[2], hp0[3], hp1[3]);
        bk0 = *(short8_t*)&u0;
        bk1 = *(short8_t*)&u1;

        // layer 3
        f32x4 a3 = mfma16(w[12], bk0, zero);
        a3 = mfma16(w[13], bk1, a3);

        // weight by wb and reduce over the 8 corners (eval low 3 bits)
        float v0 = wbv * a3[0], v1 = wbv * a3[1], v2 = wbv * a3[2], v3 = wbv * a3[3];
        #pragma unroll
        for (int s = 1; s < 8; s <<= 1) {
            v0 += __shfl_xor(v0, s);
            v1 += __shfl_xor(v1, s);
            v2 += __shfl_xor(v2, s);
            v3 += __shfl_xor(v3, s);
        }
        if (((lane & 7) == 0) && q < 2) {
            const int p = (blockIdx.x * BLOCK + ev) >> 3;
            *(float4*)(out + p * 8 + q * 4) = make_float4(v0, v1, v2, v3);
        }
    }
}

// ---- R13 single-kernel fallback (ws too small for the two-pass split) ----
template<bool BT>
__global__ __launch_bounds__(BLOCK, 5)
void ngp_mfma(const float*  __restrict__ xyz,
              const float2* __restrict__ tbl,
              const int*    __restrict__ boundp,
              const unsigned* __restrict__ wsw,
              float*        __restrict__ out,
              int ntiles)
{
    __shared__ __align__(16) unsigned lds[4096];
    const int tid  = threadIdx.x;
    const int lane = tid & 63;
    const int wv   = tid >> 6;
    const int col  = lane & 15;
    const int q    = lane >> 4;
    const int swz  = (tid ^ (tid >> 2) ^ (tid >> 4)) & 3;

    const unsigned* __restrict__ tbx = wsw + TOFF;
    const float bnd = (float)boundp[0];
    const float sc  = 0.5f / bnd;
    const f32x4 zero = {0.0f, 0.0f, 0.0f, 0.0f};

    const int ge = blockIdx.x * BLOCK + tid;
    const int pt = ge >> 3;
    const int b  = ge & 7;

    const float cxf = (xyz[pt * 3 + 0] + bnd) * sc * 512.0f;
    const float cyf = (xyz[pt * 3 + 1] + bnd) * sc * 512.0f;
    const float czf = (xyz[pt * 3 + 2] + bnd) * sc * 512.0f;
    const float c0x = fminf(fmaxf(floorf(cxf), 0.0f), 511.0f);
    const float c0y = fminf(fmaxf(floorf(cyf), 0.0f), 511.0f);
    const float c0z = fminf(fmaxf(floorf(czf), 0.0f), 511.0f);
    const float frx = cxf - c0x;
    const float fry = cyf - c0y;
    const float frz = czf - c0z;

    const unsigned kx = (unsigned)c0x + (unsigned)(b & 1);
    const unsigned ky = (unsigned)c0y + (unsigned)((b >> 1) & 1);
    const unsigned kz = (unsigned)c0z + (unsigned)((b >> 2) & 1);

    const float wb = ((b & 1) ? frx : 1.0f - frx)
                   * ((b & 2) ? fry : 1.0f - fry)
                   * ((b & 4) ? frz : 1.0f - frz);

    const unsigned kyp = ky * cP1;
    const unsigned kzp = kz * cP2;
    const unsigned X   = kx ^ kyp ^ kzp;
    unsigned gfu[11];
    float2   gff[11];
    #pragma unroll
    for (int l = 5; l < 16; ++l) {
        const int s = l - 5;
        if (BT) {
            const unsigned base = (1u << 20) + ((1u << 20) - ((1u << 20) >> s));
            gfu[l - 5] = tbx[base + (X & (kMask >> s))];
        } else {
            const unsigned idx = ((kx << s) ^ (kyp << s) ^ (kzp << s)) & kMask;
            gff[l - 5] = tbl[(size_t)l * kT + idx];
        }
    }

    unsigned gH[2][8];
    float2   gHf[2][8];
    #pragma unroll
    for (int l = 3; l < 5; ++l) {
        const int d = 5 - l;
        const unsigned qx = kx >> d, qy = ky >> d, qz = kz >> d;
        const unsigned hy0 = qy * cP1, hy1 = hy0 + cP1;
        const unsigned hz0 = qz * cP2, hz1 = hz0 + cP2;
        const unsigned x1u = qx + 1u;
        unsigned hidx[8];
        hidx[0] = (qx  ^ hy0 ^ hz0) & kMask;  hidx[1] = (x1u ^ hy0 ^ hz0) & kMask;
        hidx[2] = (qx  ^ hy1 ^ hz0) & kMask;  hidx[3] = (x1u ^ hy1 ^ hz0) & kMask;
        hidx[4] = (qx  ^ hy0 ^ hz1) & kMask;  hidx[5] = (x1u ^ hy0 ^ hz1) & kMask;
        hidx[6] = (qx  ^ hy1 ^ hz1) & kMask;  hidx[7] = (x1u ^ hy1 ^ hz1) & kMask;
        if (BT) {
            const unsigned* __restrict__ base = tbx + (size_t)(l - 3) * kT;
            #pragma unroll
            for (int c = 0; c < 8; ++c) gH[l - 3][c] = base[hidx[c]];
        } else {
            const float2* __restrict__ base = tbl + (size_t)l * kT;
            #pragma unroll
            for (int c = 0; c < 8; ++c) gHf[l - 3][c] = base[hidx[c]];
        }
    }

    float2 gc[5];
    #pragma unroll
    for (int l = 0; l < 5; ++l) {
        const int d = 5 - l;
        const unsigned m = (1u << d) - 1u;
        const float inv = 1.0f / (float)(1 << d);
        const unsigned qx = kx >> d, qy = ky >> d, qz = kz >> d;
        const float fx = (float)(kx & m) * inv;
        const float fy = (float)(ky & m) * inv;
        const float fz = (float)(kz & m) * inv;
        float2 g0, g1, g2, g3, g4, g5, g6, g7;
        if (l < 3) {
            const unsigned res = 16u << l;
            const unsigned R = res + 1u, R2 = R * R;
            const unsigned x0 = (qx < res ? qx : res);
            const unsigned x1 = (qx + 1u < res ? qx + 1u : res);
            const unsigned y0 = (qy < res ? qy : res) * R;
            const unsigned y1 = (qy + 1u < res ? qy + 1u : res) * R;
            const unsigned z0 = (qz < res ? qz : res) * R2;
            const unsigned z1 = (qz + 1u < res ? qz + 1u : res) * R2;
            const float2* __restrict__ base = tbl + (size_t)l * kT;
            g0 = base[x0 + y0 + z0]; g1 = base[x1 + y0 + z0];
            g2 = base[x0 + y1 + z0]; g3 = base[x1 + y1 + z0];
            g4 = base[x0 + y0 + z1]; g5 = base[x1 + y0 + z1];
            g6 = base[x0 + y1 + z1]; g7 = base[x1 + y1 + z1];
        } else if (BT) {
            g0 = bf2dec(gH[l - 3][0]); g1 = bf2dec(gH[l - 3][1]);
            g2 = bf2dec(gH[l - 3][2]); g3 = bf2dec(gH[l - 3][3]);
            g4 = bf2dec(gH[l - 3][4]); g5 = bf2dec(gH[l - 3][5]);
            g6 = bf2dec(gH[l - 3][6]); g7 = bf2dec(gH[l - 3][7]);
        } else {
            g0 = gHf[l - 3][0]; g1 = gHf[l - 3][1]; g2 = gHf[l - 3][2]; g3 = gHf[l - 3][3];
            g4 = gHf[l - 3][4]; g5 = gHf[l - 3][5]; g6 = gHf[l - 3][6]; g7 = gHf[l - 3][7];
        }
        const float wx1 = fx, wx0 = 1.0f - fx;
        const float wy1 = fy, wy0 = 1.0f - fy;
        const float wz1 = fz, wz0 = 1.0f - fz;
        const float w00 = wx0 * wy0, w10 = wx1 * wy0, w01 = wx0 * wy1, w11 = wx1 * wy1;
        const float a0 = w00 * wz0, a1 = w10 * wz0, a2 = w01 * wz0, a3 = w11 * wz0;
        const float a4 = w00 * wz1, a5 = w10 * wz1, a6 = w01 * wz1, a7 = w11 * wz1;
        float vx = a0 * g0.x + a1 * g1.x + a2 * g2.x + a3 * g3.x
                 + a4 * g4.x + a5 * g5.x + a6 * g6.x + a7 * g7.x;
        float vy = a0 * g0.y + a1 * g1.y + a2 * g2.y + a3 * g3.y
                 + a4 * g4.y + a5 * g5.y + a6 * g6.y + a7 * g7.y;
        gc[l] = make_float2(vx, vy);
    }

    unsigned xd[16];
    #pragma unroll
    for (int l = 0; l < 5; ++l)
        xd[l] = cvtpk(gc[l].x, gc[l].y);
    #pragma unroll
    for (int l = 5; l < 16; ++l) {
        if (BT) xd[l] = gfu[l - 5];
        else    xd[l] = cvtpk(gff[l - 5].x, gff[l - 5].y);
    }
    {
        uint4* xrow = (uint4*)(lds + tid * 16);
        xrow[swz]     = make_uint4(xd[0],  xd[1],  xd[2],  xd[3]);
        xrow[swz ^ 1] = make_uint4(xd[4],  xd[5],  xd[6],  xd[7]);
        xrow[swz ^ 2] = make_uint4(xd[8],  xd[9],  xd[10], xd[11]);
        xrow[swz ^ 3] = make_uint4(xd[12], xd[13], xd[14], xd[15]);
    }

    asm volatile("s_waitcnt lgkmcnt(0)" ::: "memory");
    __builtin_amdgcn_sched_barrier(0);

    short8_t w[14];
    {
        const short8_t* __restrict__ wfr = (const short8_t*)wsw;
        #pragma unroll
        for (int t = 0; t < 14; ++t) w[t] = wfr[t * 64 + lane];
    }

    #pragma unroll 1
    for (int g = 0; g < 4; ++g) {
        const int ev  = wv * 64 + g * 16 + col;
        const int esw = ((ev ^ (ev >> 2) ^ (ev >> 4)) & 3) ^ q;
        const short8_t xb = *(const short8_t*)(lds + ev * 16 + esw * 4);
        const float wbv = __shfl(wb, g * 16 + col, 64);

        unsigned hp0[4], hp1[4];
        #pragma unroll
        for (int mt = 0; mt < 4; ++mt) {
            f32x4 a = mfma16(w[mt], xb, zero);
            hp0[mt] = cvtpk(fmaxf(a[0], 0.0f), fmaxf(a[1], 0.0f));
            hp1[mt] = cvtpk(fmaxf(a[2], 0.0f), fmaxf(a[3], 0.0f));
        }
        uint4 u0 = make_uint4(hp0[0], hp1[0], hp0[1], hp1[1]);
        uint4 u1 = make_uint4(hp0[2], hp1[2], hp0[3], hp1[3]);
        short8_t bk0 = *(short8_t*)&u0;
        short8_t bk1 = *(short8_t*)&u1;

        #pragma unroll
        for (int mt = 0; mt < 4; ++mt) {
            f32x4 a = mfma16(w[4 + mt * 2], bk0, zero);
            a = mfma16(w[5 + mt * 2], bk1, a);
            hp0[mt] = cvtpk(fmaxf(a[0], 0.0f), fmaxf(a[1], 0.0f));
            hp1[mt] = cvtpk(fmaxf(a[2], 0.0f), fmaxf(a[3], 0.0f));
        }
        u0 = make_uint4(hp0[0], hp1[0], hp0[1], hp1[1]);
        u1 = make_uint4(hp0[2], hp1[2], hp0[3], hp1[3]);
        bk0 = *(short8_t*)&u0;
        bk1 = *(short8_t*)&u1;

        f32x4 a3 = mfma16(w[12], bk0, zero);
        a3 = mfma16(w[13], bk1, a3);

        float v0 = wbv * a3[0], v1 = wbv * a3[1], v2 = wbv * a3[2], v3 = wbv * a3[3];
        #pragma unroll
        for (int s = 1; s < 8; s <<= 1) {
            v0 += __shfl_xor(v0, s);
            v1 += __shfl_xor(v1, s);
            v2 += __shfl_xor(v2, s);
            v3 += __shfl_xor(v3, s);
        }
        if (((lane & 7) == 0) && q < 2) {
            const int p = (blockIdx.x * BLOCK + ev) >> 3;
            *(float4*)(out + p * 8 + q * 4) = make_float4(v0, v1, v2, v3);
        }
    }
}

extern "C" void kernel_launch(void* const* d_in, const int* in_sizes, int n_in,
                              void* d_out, int out_size, void* d_ws, size_t ws_size,
                              hipStream_t stream) {
    const float*  xyz = (const float*)d_in[0];
    const float2* tbl = (const float2*)d_in[1];
    const float*  W0  = (const float*)d_in[2];
    const float*  W1  = (const float*)d_in[3];
    const float*  W2  = (const float*)d_in[4];
    const int*    bnd = (const int*)d_in[5];
    float* out = (float*)d_out;

    const int npts   = in_sizes[0] / 3;
    const int total  = npts * 8;
    const int ntiles = total / BLOCK;

    const bool big2 = (ws_size >= WS_NEED2);
    const bool big  = (ws_size >= WS_NEED);
    const int ncc = big ? (1 << 19) / 256 : 0;                   // 2048
    const int ncf = big ? ((1 << 20) - (1 << 9)) / 256 : 0;      // 4094
    const int ncd = big2 ? (int)((DENSE_N + 255) / 256) : 0;     // 1233

    hipLaunchKernelGGL(prep_all, dim3(ncc + ncf + ncd + 4), dim3(256), 0, stream,
                       W0, W1, W2, tbl, (unsigned*)d_ws, ncc, ncf, ncd);

    if (big2) {
        hipLaunchKernelGGL(ngp_pa, dim3(total / 256), dim3(256), 0, stream,
                           xyz, bnd, (unsigned*)d_ws);
        hipLaunchKernelGGL(ngp_pb, dim3(ntiles), dim3(BLOCK), 0, stream,
                           xyz, bnd, (const unsigned*)d_ws, out);
    } else if (big) {
        hipLaunchKernelGGL(ngp_mfma<true>, dim3(ntiles), dim3(BLOCK), 0, stream,
                           xyz, tbl, bnd, (const unsigned*)d_ws, out, ntiles);
    } else {
        hipLaunchKernelGGL(ngp_mfma<false>, dim3(ntiles), dim3(BLOCK), 0, stream,
                           xyz, tbl, bnd, (const unsigned*)d_ws, out, ntiles);
    }
}